// Round 1
// 299.941 us; speedup vs baseline: 1.1713x; 1.1713x over previous
//
#include <hip/hip_runtime.h>
#include <math.h>

#define NCLS 100
#define NBINS 15
#define NSEG (NCLS * NBINS)
#define NTOT (2 * NSEG + NCLS)   // conf[1500] | acc[1500] | total[100] = 3100
#define PSTRIDE 3104             // padded to 64B-aligned rows (3104*4 = 12416 = 194*64)
#define RPI 8                    // rows per tile
#define GMAIN 1024               // main grid: 4 blocks/CU, all-resident (must be multiple of 16)

// Native fp32 atomic add (ds_add_f32 / global_atomic_add_f32).
__device__ __forceinline__ void fadd(float* p, float v) { unsafeAtomicAdd(p, v); }

__device__ __forceinline__ float readlane_f(float x, int l) {
    return __builtin_bit_cast(float, __builtin_amdgcn_readlane(__builtin_bit_cast(int, x), l));
}

// DPP wave64 sum step (VALU pipe only). 6-step chain -> lane 63 holds total.
template <int CTRL>
__device__ __forceinline__ float dpp_add(float x) {
    int y = __builtin_amdgcn_update_dpp(0, __builtin_bit_cast(int, x),
                                        CTRL, 0xf, 0xf, true);
    return x + __builtin_bit_cast(float, y);
}

// Lane l owns classes (2l, 2l+1); lanes 0..49 active. One float2 (dwordx2)
// load per row = 400B coalesced, replacing the old 256B+144B pair.
__device__ __forceinline__ void load_tile(
    const float* __restrict__ logits, const int* __restrict__ labels,
    int base, int N, int lane, bool act,
    float (&e0)[RPI], float (&e1)[RPI], int& labv)
{
    labv = labels[min(base + lane, N - 1)];
    const float* rp = logits + (size_t)base * NCLS + 2 * lane;
    if (base + RPI <= N) {                       // fast path: whole tile in-bounds
        #pragma unroll
        for (int r = 0; r < RPI; ++r) {
            float2 v = make_float2(-1000.f, -1000.f);
            if (act) v = *(const float2*)(rp + (size_t)r * NCLS);
            e0[r] = v.x; e1[r] = v.y;
        }
    } else {                                     // tail tile: per-row predication
        #pragma unroll
        for (int r = 0; r < RPI; ++r) {
            float2 v = make_float2(-1000.f, -1000.f);
            if (act && (base + r) < N) v = *(const float2*)(rp + (size_t)r * NCLS);
            e0[r] = v.x; e1[r] = v.y;
        }
    }
}

__device__ __forceinline__ void compute_tile(
    int base, int N, int lane, bool act, int c0, int c1,
    float (&e0)[RPI], float (&e1)[RPI], int labv,
    float& t0, float& t1, float* s_conf, float* s_acc)
{
    float s[RPI];
    // exp in place (exp(-1000) flushes to 0 for pad lanes/rows).
    #pragma unroll
    for (int r = 0; r < RPI; ++r) {
        e0[r] = __expf(e0[r]);
        e1[r] = __expf(e1[r]);
        s[r] = e0[r] + e1[r];
    }
    // 8 interleaved DPP chains (depth 6, 8-way ILP).
    #pragma unroll
    for (int r = 0; r < RPI; ++r) s[r] = dpp_add<0x111>(s[r]); // row_shr:1
    #pragma unroll
    for (int r = 0; r < RPI; ++r) s[r] = dpp_add<0x112>(s[r]); // row_shr:2
    #pragma unroll
    for (int r = 0; r < RPI; ++r) s[r] = dpp_add<0x114>(s[r]); // row_shr:4
    #pragma unroll
    for (int r = 0; r < RPI; ++r) s[r] = dpp_add<0x118>(s[r]); // row_shr:8
    #pragma unroll
    for (int r = 0; r < RPI; ++r) s[r] = dpp_add<0x142>(s[r]); // bcast:15
    #pragma unroll
    for (int r = 0; r < RPI; ++r) s[r] = dpp_add<0x143>(s[r]); // bcast:31

    // Independent row tails (rcp, bins, rare LDS atomics).
    #pragma unroll
    for (int r = 0; r < RPI; ++r) {
        const float tot = readlane_f(s[r], 63);
        const float inv = __builtin_amdgcn_rcpf(fmaxf(tot, 1e-30f));
        const int lab = (base + r < N)
                      ? __builtin_amdgcn_readlane(labv, r) : -1;
        const float p0 = e0[r] * inv;
        const float p1 = e1[r] * inv;
        t0 += p0;                                 // pad lanes/rows contribute 0
        t1 += p1;
        if (act) {
            int b0 = min((int)ceilf(p0 * 15.f) - 1, NBINS - 1);  // -1 iff p==0
            if (b0 >= 1) fadd(&s_conf[c0 * NBINS + b0], p0);     // ~0.8% lanes
            if (c0 == lab) fadd(&s_acc[c0 * NBINS + max(b0, 0)], 1.f);
            int b1 = min((int)ceilf(p1 * 15.f) - 1, NBINS - 1);
            if (b1 >= 1) fadd(&s_conf[c1 * NBINS + b1], p1);
            if (c1 == lab) fadd(&s_acc[c1 * NBINS + max(b1, 0)], 1.f);
        }
    }
}

// launch_bounds(256,4): VGPR cap 128 so the double-buffered pipeline (A+B
// register tiles ~= 34 VGPRs + live state) stays in registers; 4 blocks/CU.
__global__ __launch_bounds__(256, 4) void ece_main_kernel(
    const float* __restrict__ logits,
    const int* __restrict__ labels,
    float* __restrict__ g_hist,     // [NTOT] (fallback atomic path)
    float* __restrict__ parts,      // [GMAIN][PSTRIDE] or nullptr
    int N)
{
    __shared__ float s_conf[NSEG];
    __shared__ float s_acc[NSEG];
    __shared__ float s_total[NCLS];
    for (int i = threadIdx.x; i < NSEG; i += 256) { s_conf[i] = 0.f; s_acc[i] = 0.f; }
    if (threadIdx.x < NCLS) s_total[threadIdx.x] = 0.f;
    __syncthreads();

    const int lane   = threadIdx.x & 63;
    const int wave   = threadIdx.x >> 6;
    const int gwave  = blockIdx.x * 4 + wave;
    const int nwaves = gridDim.x * 4;
    const bool act   = (lane < NCLS / 2);   // lanes 0..49 hold classes
    const int c0 = 2 * lane;
    const int c1 = 2 * lane + 1;

    float t0 = 0.f, t1 = 0.f;               // lane-private per-class prob totals

    // Software pipeline: ping-pong register tiles, prefetch issued a full
    // tile ahead of consumption; sched_barrier pins the loads above compute.
    float A0[RPI], A1[RPI], B0[RPI], B1[RPI];
    int labA = 0, labB = 0;
    const int step = nwaves * RPI;
    int base = gwave * RPI;
    bool curA = true;
    if (base < N) load_tile(logits, labels, base, N, lane, act, A0, A1, labA);
    while (base < N) {
        const int nxt = base + step;
        if (curA) {
            if (nxt < N) {
                load_tile(logits, labels, nxt, N, lane, act, B0, B1, labB);
                __builtin_amdgcn_sched_barrier(0);
            }
            compute_tile(base, N, lane, act, c0, c1, A0, A1, labA, t0, t1, s_conf, s_acc);
        } else {
            if (nxt < N) {
                load_tile(logits, labels, nxt, N, lane, act, A0, A1, labA);
                __builtin_amdgcn_sched_barrier(0);
            }
            compute_tile(base, N, lane, act, c0, c1, B0, B1, labB, t0, t1, s_conf, s_acc);
        }
        curA = !curA;
        base = nxt;
    }

    if (act) { fadd(&s_total[c0], t0); fadd(&s_total[c1], t1); }
    __syncthreads();

    if (parts) {
        // Two-stage path: stream the block-private histogram (no atomics,
        // full-line nontemporal stores, no contention).
        float* my = parts + (size_t)blockIdx.x * PSTRIDE;
        for (int i = threadIdx.x; i < NSEG; i += 256) {
            __builtin_nontemporal_store(s_conf[i], &my[i]);
            __builtin_nontemporal_store(s_acc[i], &my[NSEG + i]);
        }
        if (threadIdx.x < NCLS)
            __builtin_nontemporal_store(s_total[threadIdx.x], &my[2 * NSEG + threadIdx.x]);
    } else {
        // Fallback: old global-atomic flush.
        for (int i = threadIdx.x; i < NSEG; i += 256) {
            float v = s_conf[i]; if (v != 0.f) fadd(&g_hist[i], v);
            float a = s_acc[i];  if (a != 0.f) fadd(&g_hist[NSEG + i], a);
        }
        if (threadIdx.x < NCLS) {
            float t = s_total[threadIdx.x];
            if (t != 0.f) fadd(&g_hist[2 * NSEG + threadIdx.x], t);
        }
    }
}

// Stage 2: fold GMAIN partial histograms into g_hist.
// grid = (ceil(NTOT/64), 4); each (block.y, wave) sums a 64-part chunk;
// lanes = 64 consecutive cells -> every load is a coalesced 256B read.
__global__ __launch_bounds__(256) void ece_reduce_kernel(
    const float* __restrict__ parts, float* __restrict__ g_hist, int nparts)
{
    const int lane = threadIdx.x & 63;
    const int wave = threadIdx.x >> 6;
    const int cell = blockIdx.x * 64 + lane;
    const int nchunks = gridDim.y * 4;
    const int chunk = blockIdx.y * 4 + wave;
    const int per = nparts / nchunks;
    float s = 0.f;
    if (cell < NTOT) {
        const float* bp = parts + (size_t)chunk * per * PSTRIDE + cell;
        #pragma unroll 8
        for (int p = 0; p < per; ++p)
            s += __builtin_nontemporal_load(&bp[(size_t)p * PSTRIDE]);
    }
    __shared__ float red[4][64];
    red[wave][lane] = s;
    __syncthreads();
    if (wave == 0) {
        float v = red[0][lane] + red[1][lane] + red[2][lane] + red[3][lane];
        if (cell < NTOT && v != 0.f) fadd(&g_hist[cell], v);   // 4 atomics/cell
    }
}

// Finalize: conf0 = total - sum_{b>=1} conf_b; per-class sce; mean.
__global__ __launch_bounds__(128) void ece_final_kernel(
    const float* __restrict__ g_hist,
    float* __restrict__ out,
    float invN)
{
    __shared__ float red[128];
    const int t = threadIdx.x;
    float s = 0.f;
    if (t < NCLS) {
        float conf0 = g_hist[2 * NSEG + t];
        float sum = 0.f;
        #pragma unroll
        for (int b = 1; b < NBINS; ++b) {
            float cb = g_hist[t * NBINS + b];
            float ab = g_hist[NSEG + t * NBINS + b];
            conf0 -= cb;
            sum += fabsf(cb - ab);
        }
        sum += fabsf(conf0 - g_hist[NSEG + t * NBINS + 0]);
        s = sum * invN;
        out[1 + t] = s;
    }
    red[t] = s;
    __syncthreads();
    #pragma unroll
    for (int off = 64; off > 0; off >>= 1) {
        if (t < off) red[t] += red[t + off];
        __syncthreads();
    }
    if (t == 0) out[0] = red[0] * (1.0f / (float)NCLS);
}

extern "C" void kernel_launch(void* const* d_in, const int* in_sizes, int n_in,
                              void* d_out, int out_size, void* d_ws, size_t ws_size,
                              hipStream_t stream)
{
    const float* logits = (const float*)d_in[0];
    const int*   labels = (const int*)d_in[1];
    const int N = in_sizes[1];
    float* out = (float*)d_out;

    float* g_hist = (float*)d_ws;                         // [NTOT]
    const size_t parts_off = ((size_t)NTOT * sizeof(float) + 255) & ~(size_t)255;
    const size_t need = parts_off + (size_t)GMAIN * PSTRIDE * sizeof(float);
    float* parts = (ws_size >= need) ? (float*)((char*)d_ws + parts_off) : nullptr;

    (void)hipMemsetAsync(d_ws, 0, (size_t)NTOT * sizeof(float), stream);

    ece_main_kernel<<<GMAIN, 256, 0, stream>>>(logits, labels, g_hist, parts, N);
    if (parts) {
        dim3 g2((NTOT + 63) / 64, 4);
        ece_reduce_kernel<<<g2, 256, 0, stream>>>(parts, g_hist, GMAIN);
    }
    ece_final_kernel<<<1, 128, 0, stream>>>(g_hist, out, 1.0f / (float)N);
}